// Round 6
// baseline (82.229 us; speedup 1.0000x reference)
//
#include <hip/hip_runtime.h>
#include <math.h>

#define NR 50      // rho grid points per dim
#define NP 200     // phi grid points per dim
#define NM 400     // mirrored width (2*NP)
#define SCADD 1e-12
#define BW 8       // numerical bandwidth of K (t=7 entry ~2e-17) = band of L (no fill)
#define LST 18     // L row stride: slots 0..7 margin zeros, 8..15 band t=8..1, 16 diag, 17 pad
#define DG 16      // diagonal slot

// ws layout (in doubles)
#define OFF_MT   7500     // M^T  [ix][iy]  (50x50)
#define OFF_AT   10000    // Atab[a][iy] 200x50
#define OFF_BT   20000    // Btab[b][ix] 200x50
#define OFF_CNT  30000    // penalty completion counter (int, re-zeroed each call)
#define OFF_EPS  40000    // eps[a][b]   200x200
#define OFF_PART 240000   // per-block penalty partials
#define NBLK_PEN 313
#define NBLK_TAB 79
#define TS 16             // eps tile edge
#define NTB 13            // ceil(200/16)

// ---------------- Kernel 1: banded solve (block 0) + eval tables ------------
__global__ __launch_bounds__(256) void solve_tables_kernel(
        const float* __restrict__ params,
        const float* __restrict__ x_rho,
        const float* __restrict__ y_rho,
        const float* __restrict__ x_phi,
        const float* __restrict__ y_phi,
        double* __restrict__ ws) {
    if (blockIdx.x != 0) {
        // ---- evaluation tables (independent of the solve) ----
        const int idx = (blockIdx.x - 1) * 256 + threadIdx.x;
        const double Lr = (double)y_rho[NR-1] - (double)y_rho[0];
        const double sigma = 0.8 * Lr / (double)(NR - 1);
        const double inv2s2 = 1.0 / (2.0 * sigma * sigma);
        if (idx < NP*NR) {
            int a = idx / NR, iy = idx % NR;
            double d = (double)y_phi[a] - (double)y_rho[iy];
            ws[OFF_AT + idx] = exp(-d*d*inv2s2);
        } else if (idx < 2*NP*NR) {
            int t = idx - NP*NR;
            int b = t / NR, ix = t % NR;
            double d = (double)x_phi[b] - (double)x_rho[ix];
            ws[OFF_BT + t] = exp(-d*d*inv2s2);
        }
        return;
    }

    // ---- block 0: the solve ----
    __shared__ double Lf0[NR * LST];   // Ky band -> L0   (7.2 KB)
    __shared__ double Lf1[NR * LST];   // Kx band -> L1
    __shared__ double Tlds[NR * 51];   // T = Ky^{-1} P   (20.4 KB)
    __shared__ double iD0[NR], iD1[NR];

    const int tid  = threadIdx.x;
    const int wave = tid >> 6;
    const int lane = tid & 63;

    for (int i = tid; i < NR*LST; i += 256) { Lf0[i] = 0.0; Lf1[i] = 0.0; }
    __syncthreads();

    const double Lr = (double)y_rho[NR-1] - (double)y_rho[0];
    const double sigma = 0.8 * Lr / (double)(NR - 1);
    const double inv2s2 = 1.0 / (2.0 * sigma * sigma);

    // build band of Ky (->Lf0) and Kx (->Lf1)
    for (int idx = tid; idx < 2*NR*(BW+1); idx += 256) {
        int m = idx / (NR*(BW+1));
        int rem = idx % (NR*(BW+1));
        int i = rem / (BW+1), t = rem % (BW+1);
        int k = i - t;
        if (k >= 0) {
            double d = m ? ((double)x_rho[i] - (double)x_rho[k])
                         : ((double)y_rho[i] - (double)y_rho[k]);
            (m ? Lf1 : Lf0)[i*LST + DG - t] = exp(-d*d*inv2s2);
        }
    }
    __syncthreads();

    // ---- barrier-free banded Cholesky: each wave owns one matrix ----
    if (wave < 2) {
        double* Lf = wave ? Lf1 : Lf0;
        double* iD = wave ? iD1 : iD0;
        for (int j = 0; j < NR; ++j) {
            const int i = j + lane;
            double s = 0.0;
            if (lane <= BW && i < NR) {
                s = Lf[i*LST + DG - lane];
                #pragma unroll
                for (int t = 1; t <= BW; ++t)       // margins absorb oob as 0
                    s -= Lf[i*LST + DG - lane - t] * Lf[j*LST + DG - t];
            }
            double dg = sqrt(__shfl(s, 0, 64));     // lane 0 holds diag dot
            double invd = 1.0 / dg;
            if (lane <= BW && i < NR) {
                Lf[i*LST + DG - lane] = (lane == 0) ? dg : s * invd;
                if (lane == 0) iD[j] = invd;
            }
        }
    }
    __syncthreads();

    // ---- Phase 1: T = Ky^{-1} P. Lane c owns column c, x[] in registers ----
    if (tid < NR) {
        const int c = tid;
        double x[NR];
        #pragma unroll
        for (int i = 0; i < NR; ++i) x[i] = (double)params[i*NR + c];
        #pragma unroll
        for (int i = 0; i < NR; ++i) {              // forward L y = p
            double s = x[i];
            #pragma unroll
            for (int t = BW; t >= 1; --t)           // t=1 (freshest dep) last
                if (i - t >= 0) s -= Lf0[i*LST + DG - t] * x[i - t];
            x[i] = s * iD0[i];
        }
        #pragma unroll
        for (int i = NR-1; i >= 0; --i) {           // backward L^T x = y
            double s = x[i];
            #pragma unroll
            for (int t = BW; t >= 1; --t)
                if (i + t < NR) s -= Lf0[(i+t)*LST + DG - t] * x[i + t];
            x[i] = s * iD0[i];
        }
        #pragma unroll
        for (int i = 0; i < NR; ++i) Tlds[i*51 + c] = x[i];
    }
    __syncthreads();

    // ---- Phase 2: row r of M solves Kx z = T[r,:]^T; write M^T coalesced ---
    if (tid < NR) {
        const int r = tid;
        double z[NR];
        #pragma unroll
        for (int i = 0; i < NR; ++i) z[i] = Tlds[r*51 + i];
        #pragma unroll
        for (int i = 0; i < NR; ++i) {
            double s = z[i];
            #pragma unroll
            for (int t = BW; t >= 1; --t)
                if (i - t >= 0) s -= Lf1[i*LST + DG - t] * z[i - t];
            z[i] = s * iD1[i];
        }
        #pragma unroll
        for (int i = NR-1; i >= 0; --i) {
            double s = z[i];
            #pragma unroll
            for (int t = BW; t >= 1; --t)
                if (i + t < NR) s -= Lf1[(i+t)*LST + DG - t] * z[i + t];
            z[i] = s * iD1[i];
        }
        double* Mt = ws + OFF_MT;
        #pragma unroll
        for (int ix = 0; ix < NR; ++ix) Mt[ix*NR + r] = z[ix];  // M^T[ix][r]
    }
}

// ---------------- Kernel 2: fused T2-slice + eps tile -----------------------
// Each block owns a 16x16 eps tile; recomputes its T2[50][16] slice in LDS.
__global__ __launch_bounds__(256) void eps_kernel(double* __restrict__ ws) {
    __shared__ double T2s[NR][TS + 1];
    const double* Mt = ws + OFF_MT;
    const double* At = ws + OFF_AT;
    const double* Bt = ws + OFF_BT;
    double* eps = ws + OFF_EPS;

    if (blockIdx.x == 0 && threadIdx.x == 0)
        *((int*)(ws + OFF_CNT)) = 0;               // arm penalty counter

    const int a0 = (blockIdx.x / NTB) * TS;
    const int b0 = (blockIdx.x % NTB) * TS;

    for (int e = threadIdx.x; e < NR*TS; e += 256) {
        int iy = e / TS, bb = e % TS, b = b0 + bb;
        double s = 0.0;
        if (b < NP) {
            #pragma unroll 10
            for (int ix = 0; ix < NR; ++ix)
                s += Mt[ix*NR + iy] * Bt[b*NR + ix];
        }
        T2s[iy][bb] = s;
    }
    __syncthreads();

    const int aa = threadIdx.x / TS, bb = threadIdx.x % TS;
    const int a = a0 + aa, b = b0 + bb;
    if (a < NP && b < NP) {
        double s = 0.0;
        #pragma unroll 10
        for (int iy = 0; iy < NR; ++iy) s += At[a*NR + iy] * T2s[iy][bb];
        eps[a*NP + b] = 0.5 * (tanh(0.1 * s) + 1.0);
    }
}

// mirror accessor over the (NP x NM) conceptual field
__device__ __forceinline__ double Emap(const double* eps, int a, int b) {
    int bb = (b < NP) ? b : (2*NP - 1 - b);
    return eps[a*NP + bb];
}
__device__ __forceinline__ double EX(const double* e, int a, int b, double g) {
    if (a == 0)      return (Emap(e,1,b)   - Emap(e,0,b))   / g + SCADD;
    if (a == NP-1)   return (Emap(e,a,b)   - Emap(e,a-1,b)) / g + SCADD;
    return (Emap(e,a+1,b) - Emap(e,a-1,b)) / (2.0*g) + SCADD;
}
__device__ __forceinline__ double EY(const double* e, int a, int b, double g) {
    if (b == 0)      return (Emap(e,a,1)   - Emap(e,a,0))   / g + SCADD;
    if (b == NM-1)   return (Emap(e,a,b)   - Emap(e,a,b-1)) / g + SCADD;
    return (Emap(e,a,b+1) - Emap(e,a,b-1)) / (2.0*g) + SCADD;
}

// ------- Kernel 3: derivatives + penalty + last-block deterministic sum -----
__global__ __launch_bounds__(256) void penalty_kernel(
        const float* __restrict__ x_phi,
        double* __restrict__ ws,
        float* __restrict__ out) {
    const double* eps = ws + OFF_EPS;
    double* part = ws + OFF_PART;
    __shared__ double sdata[256];
    __shared__ bool last;

    const int idx = blockIdx.x * blockDim.x + threadIdx.x;
    const double g = ((double)x_phi[NP-1] - (double)x_phi[0]) / (double)(NP - 1);
    const double pi_d = M_PI / 1.1;

    double local = 0.0;
    if (idx < NP*NM) {
        const int a = idx / NM, b = idx % NM;
        const double exv = EX(eps, a, b, g);
        const double eyv = EY(eps, a, b, g);
        double exx, exy, eyy;
        if (a == 0)         exx = (EX(eps,1,b,g)   - EX(eps,0,b,g))   / g;
        else if (a == NP-1) exx = (EX(eps,a,b,g)   - EX(eps,a-1,b,g)) / g;
        else                exx = (EX(eps,a+1,b,g) - EX(eps,a-1,b,g)) / (2.0*g);
        if (b == 0)         exy = (EX(eps,a,1,g)   - EX(eps,a,0,g))   / g;
        else if (b == NM-1) exy = (EX(eps,a,b,g)   - EX(eps,a,b-1,g)) / g;
        else                exy = (EX(eps,a,b+1,g) - EX(eps,a,b-1,g)) / (2.0*g);
        if (b == 0)         eyy = (EY(eps,a,1,g)   - EY(eps,a,0,g))   / g;
        else if (b == NM-1) eyy = (EY(eps,a,b,g)   - EY(eps,a,b-1,g)) / g;
        else                eyy = (EY(eps,a,b+1,g) - EY(eps,a,b-1,g)) / (2.0*g);

        double epsv = sqrt(exv*exv + eyv*eyv);
        const double epsv_min = 1e-32 / 6.0;
        if (epsv < epsv_min) epsv = epsv_min;
        const double kk = (exv*exv*eyy - 2.0*exv*eyv*exy + eyv*eyv*exx)
                          / (epsv*epsv*epsv);
        const double cc = fabs(kk * atan(epsv / Emap(eps, a, b))) - pi_d;
        double v = fmax(cc, 0.0) * g * g;
        if (!isnan(v)) local = v;
    }
    sdata[threadIdx.x] = local;
    __syncthreads();
    for (int s = 128; s > 0; s >>= 1) {
        if (threadIdx.x < s) sdata[threadIdx.x] += sdata[threadIdx.x + s];
        __syncthreads();
    }
    if (threadIdx.x == 0) {
        part[blockIdx.x] = sdata[0];
        __threadfence();                               // publish partial
        int old = atomicAdd((int*)(ws + OFF_CNT), 1);  // device-scope
        last = (old == NBLK_PEN - 1);
    }
    __syncthreads();
    if (last) {                                        // block-uniform branch
        __threadfence();                               // acquire all partials
        double s = 0.0;
        for (int i = threadIdx.x; i < NBLK_PEN; i += 256) s += part[i];
        sdata[threadIdx.x] = s;
        __syncthreads();
        for (int w = 128; w > 0; w >>= 1) {
            if (threadIdx.x < w) sdata[threadIdx.x] += sdata[threadIdx.x + w];
            __syncthreads();
        }
        if (threadIdx.x == 0) out[0] = (float)sdata[0];  // fixed order -> deterministic
    }
}

extern "C" void kernel_launch(void* const* d_in, const int* in_sizes, int n_in,
                              void* d_out, int out_size, void* d_ws, size_t ws_size,
                              hipStream_t stream) {
    const float* params = (const float*)d_in[0];
    const float* x_rho  = (const float*)d_in[1];
    const float* y_rho  = (const float*)d_in[2];
    const float* x_phi  = (const float*)d_in[3];
    const float* y_phi  = (const float*)d_in[4];
    double* ws = (double*)d_ws;
    float* out = (float*)d_out;

    solve_tables_kernel<<<1 + NBLK_TAB, 256, 0, stream>>>(
        params, x_rho, y_rho, x_phi, y_phi, ws);
    eps_kernel<<<NTB*NTB, 256, 0, stream>>>(ws);
    penalty_kernel<<<NBLK_PEN, 256, 0, stream>>>(x_phi, ws, out);
}